// Round 12
// baseline (312.996 us; speedup 1.0000x reference)
//
#include <hip/hip_runtime.h>
#include <hip/hip_cooperative_groups.h>
#include <math.h>

namespace cg = cooperative_groups;

#define BS   16
#define NMAX 64
#define NA   8400
#define NCLS 80
#define TOPK 10
#define ROWS (BS * NMAX)          // 1024
#define TOTAL (BS * NA)           // 134400
#define GRID 512
#define NTH  256

typedef unsigned long long u64;

// CIoU (clipped at 0) using precomputed atan/area of the predicted box
__device__ __forceinline__ float ciou_clip(
    float gx1, float gy1, float gx2, float gy2, float at1, float area1,
    float px1, float py1, float px2, float py2, float at2, float area2)
{
    float iw = fminf(gx2, px2) - fmaxf(gx1, px1);
    float ih = fminf(gy2, py2) - fmaxf(gy1, py1);
    float inter = fmaxf(iw, 0.f) * fmaxf(ih, 0.f);
    float uni = area1 + area2 - inter + 1e-7f;
    float iou = inter / uni;
    float cw = fmaxf(gx2, px2) - fminf(gx1, px1);
    float ch = fmaxf(gy2, py2) - fminf(gy1, py1);
    float c2 = cw * cw + ch * ch + 1e-7f;
    float dx = px1 + px2 - gx1 - gx2;
    float dy = py1 + py2 - gy1 - gy2;
    float rho2 = (dx * dx + dy * dy) * 0.25f;
    float dat = at2 - at1;
    float v = (4.0f / (float)(M_PI * M_PI)) * dat * dat;
    float alpha = v / (v - iou + (1.0f + 1e-7f));
    return fmaxf(iou - (rho2 / c2 + v * alpha), 0.f);
}

#define INS10(kk)                                                         \
    if ((kk) > L[9]) {                                                    \
        L[9] = (kk);                                                      \
        _Pragma("unroll")                                                 \
        for (int q = 9; q >= 1; q--)                                      \
            if (L[q] > L[q-1]) { u64 tt = L[q-1]; L[q-1] = L[q]; L[q] = tt; } \
    }

__global__ __launch_bounds__(NTH, 2) void fused_all(
    const float* __restrict__ score,
    const float* __restrict__ p_box,
    const float* __restrict__ anchors,
    const int*   __restrict__ gt_labels,
    const float* __restrict__ gt_box,
    const float* __restrict__ mask,
    float2* __restrict__ at2tab,
    float*  __restrict__ at1r,
    float*  __restrict__ area1r,
    u64*    __restrict__ mask64,
    float*  __restrict__ amt,
    float*  __restrict__ aov,
    int*    __restrict__ gt_idx,
    unsigned char* __restrict__ fg_arr,
    float*  __restrict__ tgt_mt,
    float*  __restrict__ pos_mt,
    float*  __restrict__ pos_ov,
    float*  __restrict__ out_bbox,
    float4* __restrict__ out_scores,
    float*  __restrict__ out_fg)
{
    cg::grid_group gg = cg::this_grid();
    int tid  = threadIdx.x;
    int gtid = blockIdx.x * NTH + tid;

    // ================= phase A: tables + zero-init =================
    for (int i = gtid; i < TOTAL; i += GRID * NTH) {
        float4 pv = ((const float4*)p_box)[i];
        float w2 = pv.z - pv.x;
        float h2 = pv.w - pv.y + 1e-7f;
        at2tab[i] = make_float2(atanf(w2 / h2), w2 * h2);
        mask64[i] = 0ull;
        if (i < ROWS) {
            float4 gb = ((const float4*)gt_box)[i];
            float w1 = gb.z - gb.x;
            float h1 = gb.w - gb.y + 1e-7f;
            at1r[i] = atanf(w1 / h1);
            area1r[i] = w1 * h1;
            pos_mt[i] = 0.f;
            pos_ov[i] = 0.f;
        }
    }
    gg.sync();

    // ========== phase B: one wave per row, grid-rect enumeration ==========
    {
        int row  = (blockIdx.x << 2) | (tid >> 6);
        int lane = tid & 63;
        if (row < ROWS && mask[row] > 0.f) {
            int b = row >> 6, n = row & 63;
            float4 gb = ((const float4*)gt_box)[row];
            float at1 = at1r[row], area1 = area1r[row];
            int lbl = gt_labels[row];
            const float* sc = score + (size_t)b * NA * NCLS + lbl;
            const float4* pb = (const float4*)p_box + (size_t)b * NA;
            const float2* t2 = at2tab + (size_t)b * NA;

            // padded candidate rects per level (exact test done per cell)
            int ilo0 = max(0,  (int)floorf(gb.x * 0.125f   - 0.5f));
            int ihi0 = min(79, (int)ceilf (gb.z * 0.125f   - 0.5f));
            int jlo0 = max(0,  (int)floorf(gb.y * 0.125f   - 0.5f));
            int jhi0 = min(79, (int)ceilf (gb.w * 0.125f   - 0.5f));
            int ilo1 = max(0,  (int)floorf(gb.x * 0.0625f  - 0.5f));
            int ihi1 = min(39, (int)ceilf (gb.z * 0.0625f  - 0.5f));
            int jlo1 = max(0,  (int)floorf(gb.y * 0.0625f  - 0.5f));
            int jhi1 = min(39, (int)ceilf (gb.w * 0.0625f  - 0.5f));
            int ilo2 = max(0,  (int)floorf(gb.x * 0.03125f - 0.5f));
            int ihi2 = min(19, (int)ceilf (gb.z * 0.03125f - 0.5f));
            int jlo2 = max(0,  (int)floorf(gb.y * 0.03125f - 0.5f));
            int jhi2 = min(19, (int)ceilf (gb.w * 0.03125f - 0.5f));
            int nx0 = max(0, ihi0 - ilo0 + 1), ny0 = max(0, jhi0 - jlo0 + 1);
            int nx1 = max(0, ihi1 - ilo1 + 1), ny1 = max(0, jhi1 - jlo1 + 1);
            int nx2 = max(0, ihi2 - ilo2 + 1), ny2 = max(0, jhi2 - jlo2 + 1);
            int c0 = nx0 * ny0;
            int c1 = c0 + nx1 * ny1;
            int T  = c1 + nx2 * ny2;

            u64 L[10];
#pragma unroll
            for (int q = 0; q < 10; q++) L[q] = 0ull;

            for (int t = lane; t < T; t += 64) {
                bool ge1 = t >= c0, ge2 = t >= c1;
                int local = t - (ge2 ? c1 : (ge1 ? c0 : 0));
                int nxl  = ge2 ? nx2  : (ge1 ? nx1  : nx0);
                int ilol = ge2 ? ilo2 : (ge1 ? ilo1 : ilo0);
                int jlol = ge2 ? jlo2 : (ge1 ? jlo1 : jlo0);
                int g    = ge2 ? 20   : (ge1 ? 40   : 80);
                int off  = ge2 ? 8000 : (ge1 ? 6400 : 0);
                float s  = ge2 ? 32.f : (ge1 ? 16.f : 8.f);
                int jj = local / nxl;
                int ii = local - jj * nxl;
                int i = ilol + ii, j = jlol + jj;
                int a = off + j * g + i;
                float ax = ((float)i + 0.5f) * s, ay = ((float)j + 0.5f) * s;
                float dmin = fminf(fminf(ax - gb.x, ay - gb.y),
                                   fminf(gb.z - ax, gb.w - ay));
                if (dmin > 1e-9f) {
                    float4 pv = pb[a];
                    float2 ta = t2[a];
                    float ov = ciou_clip(gb.x, gb.y, gb.z, gb.w, at1, area1,
                                         pv.x, pv.y, pv.z, pv.w, ta.x, ta.y);
                    float o2 = ov * ov;
                    float mt = sqrtf(sc[(size_t)a * NCLS]) * o2 * o2 * o2;
                    u64 kk = ((u64)__float_as_uint(mt) << 32) | (unsigned)(~a);
                    INS10(kk)
                }
            }
            // zero-metric tie fillers: first 64 anchors (level0 j=0, i=lane)
            {
                float ax = (float)lane * 8.f + 4.f, ay = 4.f;
                float dmin = fminf(fminf(ax - gb.x, ay - gb.y),
                                   fminf(gb.z - ax, gb.w - ay));
                if (!(dmin > 1e-9f)) {
                    u64 kk = (u64)(unsigned)(~lane);
                    INS10(kk)
                }
            }

            // top-10 across the wave
            u64 winkey = 0ull;
            for (int it = 0; it < TOPK; it++) {
                u64 m = L[0];
#pragma unroll
                for (int o = 1; o < 64; o <<= 1) {
                    u64 v = __shfl_xor(m, o);
                    if (v > m) m = v;
                }
                if (lane == it) winkey = m;
                if (L[0] == m) {
#pragma unroll
                    for (int q = 0; q < 9; q++) L[q] = L[q + 1];
                    L[9] = 0ull;
                }
            }

            if (lane < TOPK && winkey) {
                int a = (int)(~(unsigned)(winkey & 0xffffffffu));
                float mt = __uint_as_float((unsigned)(winkey >> 32));
                bool l2 = a >= 8000, l1 = (a >= 6400) && !l2;
                int loc = a - (l2 ? 8000 : (l1 ? 6400 : 0));
                int g   = l2 ? 20 : (l1 ? 40 : 80);
                float s = l2 ? 32.f : (l1 ? 16.f : 8.f);
                int j = loc / g, i = loc - j * g;
                float ax = ((float)i + 0.5f) * s, ay = ((float)j + 0.5f) * s;
                float dmin = fminf(fminf(ax - gb.x, ay - gb.y),
                                   fminf(gb.z - ax, gb.w - ay));
                if (dmin > 1e-9f) {          // mask_in_gts re-check
                    size_t idx = (size_t)b * NA + a;
                    atomicOr(&mask64[idx], 1ull << n);
                    float4 pv = pb[a];
                    float2 ta = t2[a];
                    float ov = ciou_clip(gb.x, gb.y, gb.z, gb.w, at1, area1,
                                         pv.x, pv.y, pv.z, pv.w, ta.x, ta.y);
                    amt[idx] = mt;   // benign race: read only when fg0==1
                    aov[idx] = ov;
                }
            }
        }
    }
    gg.sync();

    // ================= phase C: per-anchor resolve =================
    for (int i = gtid; i < TOTAL; i += GRID * NTH) {
        int b = i / NA, a = i - b * NA;
        u64 bits = mask64[i];
        int fg0 = __popcll(bits);
        int gi = 0, fg = (fg0 > 0);
        float mt = 0.f, ov = 0.f;
        if (fg0 == 1) {
            gi = __ffsll(bits) - 1;
            mt = amt[i];
            ov = aov[i];
        } else if (fg0 > 1) {
            float2 axy = ((const float2*)anchors)[a];
            float4 pv = ((const float4*)p_box)[i];
            float2 ta = at2tab[i];
            const float* mrow = mask + b * NMAX;
            float best = -1.f; int argn = 0;
            for (int nn = 0; nn < NMAX; nn++) {
                float v = 0.f;
                if (mrow[nn] > 0.f) {
                    int r = b * NMAX + nn;
                    float4 gbv = ((const float4*)gt_box)[r];
                    float dmin = fminf(fminf(axy.x - gbv.x, axy.y - gbv.y),
                                       fminf(gbv.z - axy.x, gbv.w - axy.y));
                    if (dmin > 1e-9f)
                        v = ciou_clip(gbv.x, gbv.y, gbv.z, gbv.w, at1r[r], area1r[r],
                                      pv.x, pv.y, pv.z, pv.w, ta.x, ta.y);
                }
                if (v > best) { best = v; argn = nn; }
            }
            gi = argn;
            ov = fmaxf(best, 0.f);
            int lbl = gt_labels[b * NMAX + argn]; if (lbl < 0) lbl = 0;
            float gath = score[((size_t)b * NA + a) * NCLS + lbl];
            float o2 = ov * ov;
            mt = sqrtf(gath) * o2 * o2 * o2;
        }
        int r = b * NMAX + gi;
        gt_idx[i] = gi;
        fg_arr[i] = (unsigned char)fg;
        tgt_mt[i] = mt;
        out_fg[i] = fg ? 1.f : 0.f;
        ((float4*)out_bbox)[i] = ((const float4*)gt_box)[r];
        if (fg) {
            atomicMax((int*)&pos_mt[r], __float_as_int(mt));
            atomicMax((int*)&pos_ov[r], __float_as_int(ov));
        }
    }
    gg.sync();

    // ================= phase D: full score tensor write =================
    const int NS4 = BS * NA * (NCLS / 4);
    for (int i = gtid; i < NS4; i += GRID * NTH) {
        int ba = i / (NCLS / 4);
        int c4 = (i - ba * (NCLS / 4)) * 4;
        float4 o = make_float4(0.f, 0.f, 0.f, 0.f);
        if (fg_arr[ba]) {
            int b = ba / NA;
            int r = b * NMAX + gt_idx[ba];
            int lbl = gt_labels[r]; if (lbl < 0) lbl = 0;
            if (lbl >= c4 && lbl < c4 + 4) {
                float val = tgt_mt[ba] * pos_ov[r] / (pos_mt[r] + 1e-9f);
                if (lbl == c4)     o.x = val;
                if (lbl == c4 + 1) o.y = val;
                if (lbl == c4 + 2) o.z = val;
                if (lbl == c4 + 3) o.w = val;
            }
        }
        out_scores[i] = o;
    }
}

extern "C" void kernel_launch(void* const* d_in, const int* in_sizes, int n_in,
                              void* d_out, int out_size, void* d_ws, size_t ws_size,
                              hipStream_t stream) {
    (void)in_sizes; (void)n_in; (void)out_size; (void)ws_size;
    const float* score     = (const float*)d_in[0];
    const float* p_box     = (const float*)d_in[1];
    const float* anchors   = (const float*)d_in[2];
    const int*   gt_labels = (const int*)d_in[3];
    const float* gt_box    = (const float*)d_in[4];
    const float* mask      = (const float*)d_in[5];

    char* w = (char*)d_ws;
    float2* at2tab  = (float2*)w;              w += (size_t)TOTAL * 8;
    u64*   mask64   = (u64*)w;                 w += (size_t)TOTAL * 8;
    float* amt      = (float*)w;               w += (size_t)TOTAL * 4;
    float* aov      = (float*)w;               w += (size_t)TOTAL * 4;
    int*   gt_idx   = (int*)w;                 w += (size_t)TOTAL * 4;
    float* tgt_mt   = (float*)w;               w += (size_t)TOTAL * 4;
    float* at1r     = (float*)w;               w += (size_t)ROWS * 4;
    float* area1r   = (float*)w;               w += (size_t)ROWS * 4;
    float* pos_mt   = (float*)w;               w += (size_t)ROWS * 4;
    float* pos_ov   = (float*)w;               w += (size_t)ROWS * 4;
    unsigned char* fg_arr = (unsigned char*)w; w += (size_t)TOTAL;

    float*  out_bbox   = (float*)d_out;                        // BS*NA*4
    float4* out_scores = (float4*)(out_bbox + (size_t)TOTAL * 4);
    float*  out_fg     = (float*)out_scores + (size_t)TOTAL * NCLS; // BS*NA

    void* args[] = {
        (void*)&score, (void*)&p_box, (void*)&anchors, (void*)&gt_labels,
        (void*)&gt_box, (void*)&mask,
        (void*)&at2tab, (void*)&at1r, (void*)&area1r, (void*)&mask64,
        (void*)&amt, (void*)&aov, (void*)&gt_idx, (void*)&fg_arr,
        (void*)&tgt_mt, (void*)&pos_mt, (void*)&pos_ov,
        (void*)&out_bbox, (void*)&out_scores, (void*)&out_fg
    };
    hipLaunchCooperativeKernel((const void*)fused_all, dim3(GRID), dim3(NTH),
                               args, 0, stream);
}

// Round 13
// 142.947 us; speedup vs baseline: 2.1896x; 2.1896x over previous
//
#include <hip/hip_runtime.h>
#include <math.h>

#define BS   16
#define NMAX 64
#define NA   8400
#define NCLS 80
#define TOPK 10
#define ROWS (BS * NMAX)          // 1024
#define TOTAL (BS * NA)           // 134400

typedef unsigned long long u64;

// CIoU (clipped at 0); at/area of both boxes precomputed by caller
__device__ __forceinline__ float ciou_clip(
    float gx1, float gy1, float gx2, float gy2, float at1, float area1,
    float px1, float py1, float px2, float py2, float at2, float area2)
{
    float iw = fminf(gx2, px2) - fmaxf(gx1, px1);
    float ih = fminf(gy2, py2) - fmaxf(gy1, py1);
    float inter = fmaxf(iw, 0.f) * fmaxf(ih, 0.f);
    float uni = area1 + area2 - inter + 1e-7f;
    float iou = inter / uni;
    float cw = fmaxf(gx2, px2) - fminf(gx1, px1);
    float ch = fmaxf(gy2, py2) - fminf(gy1, py1);
    float c2 = cw * cw + ch * ch + 1e-7f;
    float dx = px1 + px2 - gx1 - gx2;
    float dy = py1 + py2 - gy1 - gy2;
    float rho2 = (dx * dx + dy * dy) * 0.25f;
    float dat = at2 - at1;
    float v = (4.0f / (float)(M_PI * M_PI)) * dat * dat;
    float alpha = v / (v - iou + (1.0f + 1e-7f));
    return fmaxf(iou - (rho2 / c2 + v * alpha), 0.f);
}

#define INS10(kk)                                                         \
    if ((kk) > L[9]) {                                                    \
        L[9] = (kk);                                                      \
        _Pragma("unroll")                                                 \
        for (int q = 9; q >= 1; q--)                                      \
            if (L[q] > L[q-1]) { u64 tt = L[q-1]; L[q-1] = L[q]; L[q] = tt; } \
    }

// ---- k1: one block (2 waves) per row: grid-rect enumeration + top-10 ----
__global__ __launch_bounds__(128) void k1_rows(
    const float* __restrict__ score,
    const float* __restrict__ p_box,
    const int*   __restrict__ gt_labels,
    const float* __restrict__ gt_box,
    const float* __restrict__ mask,
    u64*   __restrict__ mask64,      // (BS*NA), pre-zeroed
    float* __restrict__ amt,         // (BS*NA)
    float* __restrict__ aov)         // (BS*NA)
{
    int row = blockIdx.x;
    if (mask[row] <= 0.f) return;    // uniform per block (before any sync)
    int wid  = threadIdx.x >> 6;
    int lane = threadIdx.x & 63;
    int b = row >> 6, n = row & 63;

    float4 gb = ((const float4*)gt_box)[row];
    float w1 = gb.z - gb.x;
    float h1 = gb.w - gb.y + 1e-7f;
    float at1 = atanf(w1 / h1);
    float area1 = w1 * h1;
    int lbl = gt_labels[row];
    const float* sc = score + (size_t)b * NA * NCLS + lbl;
    const float4* pb = (const float4*)p_box + (size_t)b * NA;

    // padded candidate rects per level (exact test done per cell)
    int ilo0 = max(0,  (int)floorf(gb.x * 0.125f   - 0.5f));
    int ihi0 = min(79, (int)ceilf (gb.z * 0.125f   - 0.5f));
    int jlo0 = max(0,  (int)floorf(gb.y * 0.125f   - 0.5f));
    int jhi0 = min(79, (int)ceilf (gb.w * 0.125f   - 0.5f));
    int ilo1 = max(0,  (int)floorf(gb.x * 0.0625f  - 0.5f));
    int ihi1 = min(39, (int)ceilf (gb.z * 0.0625f  - 0.5f));
    int jlo1 = max(0,  (int)floorf(gb.y * 0.0625f  - 0.5f));
    int jhi1 = min(39, (int)ceilf (gb.w * 0.0625f  - 0.5f));
    int ilo2 = max(0,  (int)floorf(gb.x * 0.03125f - 0.5f));
    int ihi2 = min(19, (int)ceilf (gb.z * 0.03125f - 0.5f));
    int jlo2 = max(0,  (int)floorf(gb.y * 0.03125f - 0.5f));
    int jhi2 = min(19, (int)ceilf (gb.w * 0.03125f - 0.5f));
    int nx0 = max(0, ihi0 - ilo0 + 1), ny0 = max(0, jhi0 - jlo0 + 1);
    int nx1 = max(0, ihi1 - ilo1 + 1), ny1 = max(0, jhi1 - jlo1 + 1);
    int nx2 = max(0, ihi2 - ilo2 + 1), ny2 = max(0, jhi2 - jlo2 + 1);
    int c0 = nx0 * ny0;
    int c1 = c0 + nx1 * ny1;
    int T  = c1 + nx2 * ny2;

    u64 L[10];
#pragma unroll
    for (int q = 0; q < 10; q++) L[q] = 0ull;

    for (int t = threadIdx.x; t < T; t += 128) {
        bool ge1 = t >= c0, ge2 = t >= c1;
        int local = t - (ge2 ? c1 : (ge1 ? c0 : 0));
        int nxl  = ge2 ? nx2  : (ge1 ? nx1  : nx0);
        int ilol = ge2 ? ilo2 : (ge1 ? ilo1 : ilo0);
        int jlol = ge2 ? jlo2 : (ge1 ? jlo1 : jlo0);
        int g    = ge2 ? 20   : (ge1 ? 40   : 80);
        int off  = ge2 ? 8000 : (ge1 ? 6400 : 0);
        float s  = ge2 ? 32.f : (ge1 ? 16.f : 8.f);
        int jj = local / nxl;
        int ii = local - jj * nxl;
        int i = ilol + ii, j = jlol + jj;
        int a = off + j * g + i;
        float ax = ((float)i + 0.5f) * s, ay = ((float)j + 0.5f) * s;
        float dmin = fminf(fminf(ax - gb.x, ay - gb.y),
                           fminf(gb.z - ax, gb.w - ay));
        if (dmin > 1e-9f) {
            float4 pv = pb[a];
            float w2 = pv.z - pv.x;
            float h2 = pv.w - pv.y + 1e-7f;
            float ov = ciou_clip(gb.x, gb.y, gb.z, gb.w, at1, area1,
                                 pv.x, pv.y, pv.z, pv.w,
                                 atanf(w2 / h2), w2 * h2);
            float o2 = ov * ov;
            float mt = sqrtf(sc[(size_t)a * NCLS]) * o2 * o2 * o2;
            u64 kk = ((u64)__float_as_uint(mt) << 32) | (unsigned)(~a);
            INS10(kk)
        }
    }
    // zero-metric tie fillers (wave 0 only): first 64 anchors, outside-box.
    // >=32 of them are outside (box width <256 px covers <=32 stride-8 cols),
    // covering all index-ordered zero-tie selections of lax.top_k.
    if (wid == 0) {
        float ax = (float)lane * 8.f + 4.f, ay = 4.f;
        float dmin = fminf(fminf(ax - gb.x, ay - gb.y),
                           fminf(gb.z - ax, gb.w - ay));
        if (!(dmin > 1e-9f)) {
            u64 kk = (u64)(unsigned)(~lane);
            INS10(kk)
        }
    }

    // per-wave top-10 -> LDS
    __shared__ u64 skey[2 * TOPK];
    u64 wk = 0ull;
    for (int it = 0; it < TOPK; it++) {
        u64 m = L[0];
#pragma unroll
        for (int o = 1; o < 64; o <<= 1) {
            u64 v = __shfl_xor(m, o);
            if (v > m) m = v;
        }
        if (lane == it) wk = m;
        if (L[0] == m) {
#pragma unroll
            for (int q = 0; q < 9; q++) L[q] = L[q + 1];
            L[9] = 0ull;
        }
    }
    if (lane < TOPK) skey[wid * TOPK + lane] = wk;
    __syncthreads();

    // wave 0 merges the 20 candidates -> final top-10, processes winners
    if (wid == 0) {
        u64 ck = (lane < 2 * TOPK) ? skey[lane] : 0ull;
        u64 winkey = 0ull;
        for (int it = 0; it < TOPK; it++) {
            u64 m = ck;
#pragma unroll
            for (int o = 1; o < 64; o <<= 1) {
                u64 v = __shfl_xor(m, o);
                if (v > m) m = v;
            }
            if (lane == it) winkey = m;
            if (ck == m) ck = 0ull;
        }
        if (lane < TOPK && winkey) {
            int a = (int)(~(unsigned)(winkey & 0xffffffffu));
            float mt = __uint_as_float((unsigned)(winkey >> 32));
            bool l2a = a >= 8000, l1a = (a >= 6400) && !l2a;
            int loc = a - (l2a ? 8000 : (l1a ? 6400 : 0));
            int g   = l2a ? 20 : (l1a ? 40 : 80);
            float s = l2a ? 32.f : (l1a ? 16.f : 8.f);
            int j = loc / g, i = loc - j * g;
            float ax = ((float)i + 0.5f) * s, ay = ((float)j + 0.5f) * s;
            float dmin = fminf(fminf(ax - gb.x, ay - gb.y),
                               fminf(gb.z - ax, gb.w - ay));
            if (dmin > 1e-9f) {          // mask_in_gts re-check
                size_t idx = (size_t)b * NA + a;
                atomicOr(&mask64[idx], 1ull << n);
                float4 pv = pb[a];
                float w2 = pv.z - pv.x;
                float h2 = pv.w - pv.y + 1e-7f;
                float ov = ciou_clip(gb.x, gb.y, gb.z, gb.w, at1, area1,
                                     pv.x, pv.y, pv.z, pv.w,
                                     atanf(w2 / h2), w2 * h2);
                amt[idx] = mt;   // benign: read only when fg0==1
                aov[idx] = ov;
            }
        }
    }
}

// ---- k3: per-anchor resolve ----
__global__ __launch_bounds__(256) void k3_resolve(
    const float* __restrict__ score,
    const float* __restrict__ p_box,
    const float* __restrict__ anchors,
    const int*   __restrict__ gt_labels,
    const float* __restrict__ gt_box,
    const float* __restrict__ mask,
    const u64*   __restrict__ mask64,
    const float* __restrict__ amt,
    const float* __restrict__ aov,
    int* __restrict__ gt_idx,
    unsigned char* __restrict__ fg_arr,
    float* __restrict__ tgt_mt,
    float* __restrict__ out_bbox,
    float* __restrict__ out_fg,
    float* __restrict__ pos_mt,      // int-atomicMax on float bits (>=0)
    float* __restrict__ pos_ov)
{
    int i = blockIdx.x * 256 + threadIdx.x;
    if (i >= TOTAL) return;
    int b = i / NA, a = i - b * NA;
    u64 bits = mask64[i];
    int fg0 = __popcll(bits);
    int gi = 0, fg = (fg0 > 0);
    float mt = 0.f, ov = 0.f;
    if (fg0 == 1) {
        gi = __ffsll(bits) - 1;
        mt = amt[i];
        ov = aov[i];
    } else if (fg0 > 1) {
        float2 axy = ((const float2*)anchors)[a];
        float4 pv = ((const float4*)p_box)[i];
        float w2 = pv.z - pv.x;
        float h2 = pv.w - pv.y + 1e-7f;
        float at2 = atanf(w2 / h2);
        float area2 = w2 * h2;
        const float* mrow = mask + b * NMAX;
        float best = -1.f; int argn = 0;
        for (int nn = 0; nn < NMAX; nn++) {
            float v = 0.f;
            if (mrow[nn] > 0.f) {
                int r = b * NMAX + nn;
                float4 gbv = ((const float4*)gt_box)[r];
                float dmin = fminf(fminf(axy.x - gbv.x, axy.y - gbv.y),
                                   fminf(gbv.z - axy.x, gbv.w - axy.y));
                if (dmin > 1e-9f) {
                    float w1 = gbv.z - gbv.x;
                    float h1 = gbv.w - gbv.y + 1e-7f;
                    v = ciou_clip(gbv.x, gbv.y, gbv.z, gbv.w,
                                  atanf(w1 / h1), w1 * h1,
                                  pv.x, pv.y, pv.z, pv.w, at2, area2);
                }
            }
            if (v > best) { best = v; argn = nn; }
        }
        gi = argn;
        ov = fmaxf(best, 0.f);
        int lbl = gt_labels[b * NMAX + argn]; if (lbl < 0) lbl = 0;
        float gath = score[((size_t)b * NA + a) * NCLS + lbl];
        float o2 = ov * ov;
        mt = sqrtf(gath) * o2 * o2 * o2;
    }
    int r = b * NMAX + gi;
    gt_idx[i] = gi;
    fg_arr[i] = (unsigned char)fg;
    tgt_mt[i] = mt;
    out_fg[i] = fg ? 1.f : 0.f;
    ((float4*)out_bbox)[i] = ((const float4*)gt_box)[r];
    if (fg) {
        atomicMax((int*)&pos_mt[r], __float_as_int(mt));
        atomicMax((int*)&pos_ov[r], __float_as_int(ov));
    }
}

// ---- k5: full score tensor write (zeros + sparse values), float4 lanes ----
__global__ __launch_bounds__(256) void k5_full(
    const int*   __restrict__ gt_idx,
    const unsigned char* __restrict__ fg_arr,
    const float* __restrict__ tgt_mt,
    const int*   __restrict__ gt_labels,
    const float* __restrict__ pos_mt,
    const float* __restrict__ pos_ov,
    float4* __restrict__ out_scores)     // BS*NA*NCLS/4 float4s
{
    int i = blockIdx.x * 256 + threadIdx.x;
    if (i >= TOTAL * (NCLS / 4)) return;
    int ba = i / (NCLS / 4);
    int c4 = (i - ba * (NCLS / 4)) * 4;
    float4 o = make_float4(0.f, 0.f, 0.f, 0.f);
    if (fg_arr[ba]) {
        int b = ba / NA;
        int r = b * NMAX + gt_idx[ba];
        int lbl = gt_labels[r]; if (lbl < 0) lbl = 0;
        if (lbl >= c4 && lbl < c4 + 4) {
            float val = tgt_mt[ba] * pos_ov[r] / (pos_mt[r] + 1e-9f);
            if (lbl == c4)     o.x = val;
            if (lbl == c4 + 1) o.y = val;
            if (lbl == c4 + 2) o.z = val;
            if (lbl == c4 + 3) o.w = val;
        }
    }
    out_scores[i] = o;
}

extern "C" void kernel_launch(void* const* d_in, const int* in_sizes, int n_in,
                              void* d_out, int out_size, void* d_ws, size_t ws_size,
                              hipStream_t stream) {
    (void)in_sizes; (void)n_in; (void)out_size; (void)ws_size;
    const float* score     = (const float*)d_in[0];
    const float* p_box     = (const float*)d_in[1];
    const float* anchors   = (const float*)d_in[2];
    const int*   gt_labels = (const int*)d_in[3];
    const float* gt_box    = (const float*)d_in[4];
    const float* mask      = (const float*)d_in[5];

    char* w = (char*)d_ws;
    u64*   mask64   = (u64*)w;                 w += (size_t)TOTAL * 8;
    float* pos_mt   = (float*)w;               w += (size_t)ROWS * 4;
    float* pos_ov   = (float*)w;               w += (size_t)ROWS * 4;
    float* amt      = (float*)w;               w += (size_t)TOTAL * 4;
    float* aov      = (float*)w;               w += (size_t)TOTAL * 4;
    int*   gt_idx   = (int*)w;                 w += (size_t)TOTAL * 4;
    float* tgt_mt   = (float*)w;               w += (size_t)TOTAL * 4;
    unsigned char* fg_arr = (unsigned char*)w; w += (size_t)TOTAL;

    float*  out_bbox   = (float*)d_out;                        // BS*NA*4
    float4* out_scores = (float4*)(out_bbox + (size_t)TOTAL * 4);
    float*  out_fg     = (float*)out_scores + (size_t)TOTAL * NCLS; // BS*NA

    // one memset covers mask64 + pos_mt + pos_ov (contiguous)
    hipMemsetAsync(mask64, 0, (size_t)TOTAL * 8 + (size_t)ROWS * 8, stream);

    hipLaunchKernelGGL(k1_rows, dim3(ROWS), dim3(128), 0, stream,
                       score, p_box, gt_labels, gt_box, mask,
                       mask64, amt, aov);
    hipLaunchKernelGGL(k3_resolve, dim3((TOTAL + 255) / 256), dim3(256), 0, stream,
                       score, p_box, anchors, gt_labels, gt_box, mask,
                       mask64, amt, aov,
                       gt_idx, fg_arr, tgt_mt, out_bbox, out_fg, pos_mt, pos_ov);
    hipLaunchKernelGGL(k5_full, dim3((TOTAL * (NCLS / 4) + 255) / 256), dim3(256), 0, stream,
                       gt_idx, fg_arr, tgt_mt, gt_labels, pos_mt, pos_ov,
                       (float4*)out_scores);
}